// Round 3
// baseline (275.589 us; speedup 1.0000x reference)
//
#include <hip/hip_runtime.h>

#define NN 50000
#define NE 800000
#define DD 128
#define SCAN_T 1024
#define CHUNK ((NN + SCAN_T - 1) / SCAN_T)   // 49

__device__ __forceinline__ unsigned short f2bf(float x) {
    unsigned u = __float_as_uint(x);
    unsigned r = u + 0x7FFF + ((u >> 16) & 1);   // round-to-nearest-even
    return (unsigned short)(r >> 16);
}
__device__ __forceinline__ float bf2f(unsigned short x) {
    return __uint_as_float((unsigned)x << 16);
}

__global__ void deg_kernel(const int* __restrict__ src, const int* __restrict__ dst,
                           int* __restrict__ out_deg, int* __restrict__ in_deg) {
    int i = blockIdx.x * blockDim.x + threadIdx.x;
    if (i < NE) {
        atomicAdd(&out_deg[src[i]], 1);
        atomicAdd(&in_deg[dst[i]], 1);
    }
}

// Single-block exclusive scan of in_deg -> cursor (each thread owns a contiguous chunk).
__global__ void scan_kernel(const int* __restrict__ in_deg, int* __restrict__ cursor) {
    __shared__ int sums[SCAN_T];
    int t = threadIdx.x;
    int b = t * CHUNK;
    int s = 0;
    for (int k = 0; k < CHUNK; k++) {
        int i = b + k;
        if (i < NN) s += in_deg[i];
    }
    sums[t] = s;
    __syncthreads();
    for (int off = 1; off < SCAN_T; off <<= 1) {
        int x = (t >= off) ? sums[t - off] : 0;
        __syncthreads();
        sums[t] += x;
        __syncthreads();
    }
    int excl = sums[t] - s;
    for (int k = 0; k < CHUNK; k++) {
        int i = b + k;
        if (i < NN) {
            cursor[i] = excl;
            excl += in_deg[i];
        }
    }
}

// Counting-sort edges by dst; cursor advances from node_base to node_end.
__global__ void sort_kernel(const int* __restrict__ src, const int* __restrict__ dst,
                            int* __restrict__ cursor, int* __restrict__ sorted_src) {
    int e = blockIdx.x * blockDim.x + threadIdx.x;
    if (e < NE) {
        int pos = atomicAdd(&cursor[dst[e]], 1);
        sorted_src[pos] = src[e];
    }
}

// h[n,:] = emb[feat[n],:] * out_deg_norm(n), stored bf16. One wave per node.
__global__ void h_kernel(const int* __restrict__ feat, const int* __restrict__ out_deg,
                         const float* __restrict__ emb, ushort2* __restrict__ h) {
    int wid = (blockIdx.x * blockDim.x + threadIdx.x) >> 6;
    int lane = threadIdx.x & 63;
    if (wid >= NN) return;
    int f = feat[wid];
    float nl = rsqrtf((float)max(out_deg[wid], 1));
    float2 v = ((const float2*)(emb + (size_t)f * DD))[lane];
    h[(size_t)wid * 64 + lane] = make_ushort2(f2bf(v.x * nl), f2bf(v.y * nl));
}

// One wave per dst node, bf16 h rows, fp32 accumulate, fused norm_r + bias.
__global__ void gatherA_kernel(const ushort2* __restrict__ h, const int* __restrict__ cursor,
                               const int* __restrict__ in_deg, const int* __restrict__ sorted,
                               const float* __restrict__ bias, float* __restrict__ out) {
    int wid = (blockIdx.x * blockDim.x + threadIdx.x) >> 6;
    int lane = threadIdx.x & 63;
    if (wid >= NN) return;
    int cnt = in_deg[wid];
    int beg = cursor[wid] - cnt;   // cursor holds node_end after sort
    float ax = 0.f, ay = 0.f;
    int j = 0;
    for (; j + 1 < cnt; j += 2) {
        int s0 = sorted[beg + j];
        int s1 = sorted[beg + j + 1];
        ushort2 v0 = h[(size_t)s0 * 64 + lane];
        ushort2 v1 = h[(size_t)s1 * 64 + lane];
        ax += bf2f(v0.x) + bf2f(v1.x);
        ay += bf2f(v0.y) + bf2f(v1.y);
    }
    if (j < cnt) {
        int s0 = sorted[beg + j];
        ushort2 v0 = h[(size_t)s0 * 64 + lane];
        ax += bf2f(v0.x);
        ay += bf2f(v0.y);
    }
    float nr = rsqrtf((float)max(cnt, 1));
    float2 b = ((const float2*)bias)[lane];
    ((float2*)(out + (size_t)wid * DD))[lane] = make_float2(ax * nr + b.x, ay * nr + b.y);
}

// Fallback (small ws): gather straight from fp32 embedding with per-edge lookups.
__global__ void gatherB_kernel(const int* __restrict__ feat, const float* __restrict__ emb,
                               const int* __restrict__ out_deg, const int* __restrict__ cursor,
                               const int* __restrict__ in_deg, const int* __restrict__ sorted,
                               const float* __restrict__ bias, float* __restrict__ out) {
    int wid = (blockIdx.x * blockDim.x + threadIdx.x) >> 6;
    int lane = threadIdx.x & 63;
    if (wid >= NN) return;
    int cnt = in_deg[wid];
    int beg = cursor[wid] - cnt;
    float2 acc = make_float2(0.f, 0.f);
    for (int j = 0; j < cnt; j++) {
        int s0 = sorted[beg + j];
        float nl0 = rsqrtf((float)max(out_deg[s0], 1));
        float2 v0 = ((const float2*)(emb + (size_t)feat[s0] * DD))[lane];
        acc.x += v0.x * nl0;
        acc.y += v0.y * nl0;
    }
    float nr = rsqrtf((float)max(cnt, 1));
    float2 b = ((const float2*)bias)[lane];
    ((float2*)(out + (size_t)wid * DD))[lane] = make_float2(acc.x * nr + b.x, acc.y * nr + b.y);
}

extern "C" void kernel_launch(void* const* d_in, const int* in_sizes, int n_in,
                              void* d_out, int out_size, void* d_ws, size_t ws_size,
                              hipStream_t stream) {
    const int* feat = (const int*)d_in[0];
    const int* src  = (const int*)d_in[1];
    const int* dst  = (const int*)d_in[2];
    const float* emb  = (const float*)d_in[3];
    const float* bias = (const float*)d_in[4];
    float* out = (float*)d_out;

    int* out_deg = (int*)d_ws;            // NN
    int* in_deg  = out_deg + NN;          // NN
    int* cursor  = in_deg + NN;           // NN
    int* sorted  = cursor + NN;           // NE
    ushort2* h   = (ushort2*)(sorted + NE); // NN*64 ushort2 = 12.8 MB

    size_t need_bf16 = (size_t)(3 * NN + NE) * sizeof(int) + (size_t)NN * 64 * sizeof(ushort2);

    hipMemsetAsync(out_deg, 0, 2 * NN * sizeof(int), stream);

    deg_kernel<<<(NE + 255) / 256, 256, 0, stream>>>(src, dst, out_deg, in_deg);
    scan_kernel<<<1, SCAN_T, 0, stream>>>(in_deg, cursor);
    sort_kernel<<<(NE + 255) / 256, 256, 0, stream>>>(src, dst, cursor, sorted);

    int gblocks = (NN * 64 + 255) / 256;
    if (ws_size >= need_bf16) {
        h_kernel<<<gblocks, 256, 0, stream>>>(feat, out_deg, emb, h);
        gatherA_kernel<<<gblocks, 256, 0, stream>>>(h, cursor, in_deg, sorted, bias, out);
    } else {
        gatherB_kernel<<<gblocks, 256, 0, stream>>>(feat, emb, out_deg, cursor, in_deg,
                                                    sorted, bias, out);
    }
}

// Round 4
// 177.217 us; speedup vs baseline: 1.5551x; 1.5551x over previous
//
#include <hip/hip_runtime.h>

#define NN 50000
#define NE 800000
#define DD 128
#define NB ((NN + 255) / 256)   // 196 blocks for scan

__device__ __forceinline__ unsigned short f2bf(float x) {
    unsigned u = __float_as_uint(x);
    unsigned r = u + 0x7FFF + ((u >> 16) & 1);   // round-to-nearest-even
    return (unsigned short)(r >> 16);
}
__device__ __forceinline__ float bf2f(unsigned short x) {
    return __uint_as_float((unsigned)x << 16);
}

__global__ void deg_kernel(const int* __restrict__ src, const int* __restrict__ dst,
                           int* __restrict__ out_deg, int* __restrict__ in_deg) {
    int i = blockIdx.x * blockDim.x + threadIdx.x;
    if (i < NE) {
        atomicAdd(&out_deg[src[i]], 1);
        atomicAdd(&in_deg[dst[i]], 1);
    }
}

// Per-block partial sums of in_deg
__global__ void partial_kernel(const int* __restrict__ in_deg, int* __restrict__ part) {
    __shared__ int tmp[256];
    int t = threadIdx.x;
    int i = blockIdx.x * 256 + t;
    tmp[t] = (i < NN) ? in_deg[i] : 0;
    __syncthreads();
    for (int off = 128; off > 0; off >>= 1) {
        if (t < off) tmp[t] += tmp[t + off];
        __syncthreads();
    }
    if (t == 0) part[blockIdx.x] = tmp[0];
}

// Single block: exclusive scan of the NB partials (NB=196 <= 256)
__global__ void scanpart_kernel(int* __restrict__ part) {
    __shared__ int tmp[256];
    int t = threadIdx.x;
    int v = (t < NB) ? part[t] : 0;
    tmp[t] = v;
    __syncthreads();
    for (int off = 1; off < 256; off <<= 1) {
        int x = (t >= off) ? tmp[t - off] : 0;
        __syncthreads();
        tmp[t] += x;
        __syncthreads();
    }
    if (t < NB) part[t] = tmp[t] - v;   // exclusive block base
}

// Per-element exclusive scan -> cursor (counting-sort bases; sort advances them)
__global__ void base_kernel(const int* __restrict__ in_deg, const int* __restrict__ part,
                            int* __restrict__ cursor) {
    __shared__ int tmp[256];
    int t = threadIdx.x;
    int i = blockIdx.x * 256 + t;
    int v = (i < NN) ? in_deg[i] : 0;
    tmp[t] = v;
    __syncthreads();
    for (int off = 1; off < 256; off <<= 1) {
        int x = (t >= off) ? tmp[t - off] : 0;
        __syncthreads();
        tmp[t] += x;
        __syncthreads();
    }
    if (i < NN) cursor[i] = part[blockIdx.x] + tmp[t] - v;   // exclusive
}

// Counting-sort edges by dst; cursor advances from node_base to node_end.
__global__ void sort_kernel(const int* __restrict__ src, const int* __restrict__ dst,
                            int* __restrict__ cursor, int* __restrict__ sorted_src) {
    int e = blockIdx.x * blockDim.x + threadIdx.x;
    if (e < NE) {
        int pos = atomicAdd(&cursor[dst[e]], 1);
        sorted_src[pos] = src[e];
    }
}

// h[n,:] = emb[feat[n],:] * out_deg_norm(n), stored bf16. One wave per node.
__global__ void h_kernel(const int* __restrict__ feat, const int* __restrict__ out_deg,
                         const float* __restrict__ emb, ushort2* __restrict__ h) {
    int wid = (blockIdx.x * blockDim.x + threadIdx.x) >> 6;
    int lane = threadIdx.x & 63;
    if (wid >= NN) return;
    int f = feat[wid];
    float nl = rsqrtf((float)max(out_deg[wid], 1));
    float2 v = ((const float2*)(emb + (size_t)f * DD))[lane];
    h[(size_t)wid * 64 + lane] = make_ushort2(f2bf(v.x * nl), f2bf(v.y * nl));
}

// One wave per dst node. Indices batch-loaded (coalesced) and shfl-broadcast;
// row loop unrolled x4 for memory-level parallelism. fp32 accumulate.
__global__ void gatherA_kernel(const ushort2* __restrict__ h, const int* __restrict__ cursor,
                               const int* __restrict__ in_deg, const int* __restrict__ sorted,
                               const float* __restrict__ bias, float* __restrict__ out) {
    int wid = (blockIdx.x * blockDim.x + threadIdx.x) >> 6;
    int lane = threadIdx.x & 63;
    if (wid >= NN) return;
    int cnt = in_deg[wid];
    int beg = cursor[wid] - cnt;   // cursor holds node_end after sort
    float ax = 0.f, ay = 0.f;
    for (int base = 0; base < cnt; base += 64) {
        int m = min(cnt - base, 64);
        int idx = (lane < m) ? sorted[beg + base + lane] : 0;
        int j = 0;
        for (; j + 3 < m; j += 4) {
            int s0 = __shfl(idx, j);
            int s1 = __shfl(idx, j + 1);
            int s2 = __shfl(idx, j + 2);
            int s3 = __shfl(idx, j + 3);
            ushort2 v0 = h[(size_t)s0 * 64 + lane];
            ushort2 v1 = h[(size_t)s1 * 64 + lane];
            ushort2 v2 = h[(size_t)s2 * 64 + lane];
            ushort2 v3 = h[(size_t)s3 * 64 + lane];
            ax += bf2f(v0.x) + bf2f(v1.x) + bf2f(v2.x) + bf2f(v3.x);
            ay += bf2f(v0.y) + bf2f(v1.y) + bf2f(v2.y) + bf2f(v3.y);
        }
        for (; j < m; j++) {
            int s0 = __shfl(idx, j);
            ushort2 v0 = h[(size_t)s0 * 64 + lane];
            ax += bf2f(v0.x);
            ay += bf2f(v0.y);
        }
    }
    float nr = rsqrtf((float)max(cnt, 1));
    float2 b = ((const float2*)bias)[lane];
    ((float2*)(out + (size_t)wid * DD))[lane] = make_float2(ax * nr + b.x, ay * nr + b.y);
}

// Fallback (small ws): gather straight from fp32 embedding with per-edge lookups.
__global__ void gatherB_kernel(const int* __restrict__ feat, const float* __restrict__ emb,
                               const int* __restrict__ out_deg, const int* __restrict__ cursor,
                               const int* __restrict__ in_deg, const int* __restrict__ sorted,
                               const float* __restrict__ bias, float* __restrict__ out) {
    int wid = (blockIdx.x * blockDim.x + threadIdx.x) >> 6;
    int lane = threadIdx.x & 63;
    if (wid >= NN) return;
    int cnt = in_deg[wid];
    int beg = cursor[wid] - cnt;
    float2 acc = make_float2(0.f, 0.f);
    for (int j = 0; j < cnt; j++) {
        int s0 = sorted[beg + j];
        float nl0 = rsqrtf((float)max(out_deg[s0], 1));
        float2 v0 = ((const float2*)(emb + (size_t)feat[s0] * DD))[lane];
        acc.x += v0.x * nl0;
        acc.y += v0.y * nl0;
    }
    float nr = rsqrtf((float)max(cnt, 1));
    float2 b = ((const float2*)bias)[lane];
    ((float2*)(out + (size_t)wid * DD))[lane] = make_float2(acc.x * nr + b.x, acc.y * nr + b.y);
}

extern "C" void kernel_launch(void* const* d_in, const int* in_sizes, int n_in,
                              void* d_out, int out_size, void* d_ws, size_t ws_size,
                              hipStream_t stream) {
    const int* feat = (const int*)d_in[0];
    const int* src  = (const int*)d_in[1];
    const int* dst  = (const int*)d_in[2];
    const float* emb  = (const float*)d_in[3];
    const float* bias = (const float*)d_in[4];
    float* out = (float*)d_out;

    int* out_deg = (int*)d_ws;              // NN
    int* in_deg  = out_deg + NN;            // NN
    int* cursor  = in_deg + NN;             // NN
    int* part    = cursor + NN;             // 256
    int* sorted  = part + 256;              // NE
    ushort2* h   = (ushort2*)(sorted + NE); // NN*64 ushort2 = 12.8 MB

    size_t need_bf16 = (size_t)(3 * NN + 256 + NE) * sizeof(int)
                     + (size_t)NN * 64 * sizeof(ushort2);

    hipMemsetAsync(out_deg, 0, 2 * NN * sizeof(int), stream);

    deg_kernel<<<(NE + 255) / 256, 256, 0, stream>>>(src, dst, out_deg, in_deg);
    partial_kernel<<<NB, 256, 0, stream>>>(in_deg, part);
    scanpart_kernel<<<1, 256, 0, stream>>>(part);
    base_kernel<<<NB, 256, 0, stream>>>(in_deg, part, cursor);
    sort_kernel<<<(NE + 255) / 256, 256, 0, stream>>>(src, dst, cursor, sorted);

    int gblocks = (NN * 64 + 255) / 256;
    if (ws_size >= need_bf16) {
        h_kernel<<<gblocks, 256, 0, stream>>>(feat, out_deg, emb, h);
        gatherA_kernel<<<gblocks, 256, 0, stream>>>(h, cursor, in_deg, sorted, bias, out);
    } else {
        gatherB_kernel<<<gblocks, 256, 0, stream>>>(feat, emb, out_deg, cursor, in_deg,
                                                    sorted, bias, out);
    }
}

// Round 5
// 148.278 us; speedup vs baseline: 1.8586x; 1.1952x over previous
//
#include <hip/hip_runtime.h>

#define NN 50000
#define NE 800000
#define DD 128
#define NB ((NN + 255) / 256)   // 196 blocks for scan

__device__ __forceinline__ unsigned short f2bf(float x) {
    unsigned u = __float_as_uint(x);
    unsigned r = u + 0x7FFF + ((u >> 16) & 1);   // round-to-nearest-even
    return (unsigned short)(r >> 16);
}
__device__ __forceinline__ float bf2f(unsigned short x) {
    return __uint_as_float((unsigned)x << 16);
}

// Histogram both degrees (padded counters to kill same-line serialization) and
// record each edge's within-destination rank for the atomic-free placement pass.
__global__ void degrank_kernel(const int* __restrict__ src, const int* __restrict__ dst,
                               int* __restrict__ out_deg_p, int* __restrict__ in_deg_p,
                               int* __restrict__ rank, int pad) {
    int e = blockIdx.x * blockDim.x + threadIdx.x;
    if (e < NE) {
        atomicAdd(&out_deg_p[src[e] * pad], 1);
        rank[e] = atomicAdd(&in_deg_p[dst[e] * pad], 1);
    }
}

// Per-block partial sums of padded in_deg
__global__ void partial_kernel(const int* __restrict__ in_deg_p, int* __restrict__ part, int pad) {
    __shared__ int tmp[256];
    int t = threadIdx.x;
    int i = blockIdx.x * 256 + t;
    tmp[t] = (i < NN) ? in_deg_p[i * pad] : 0;
    __syncthreads();
    for (int off = 128; off > 0; off >>= 1) {
        if (t < off) tmp[t] += tmp[t + off];
        __syncthreads();
    }
    if (t == 0) part[blockIdx.x] = tmp[0];
}

// Single block: exclusive scan of the NB partials (NB=196 <= 256)
__global__ void scanpart_kernel(int* __restrict__ part) {
    __shared__ int tmp[256];
    int t = threadIdx.x;
    int v = (t < NB) ? part[t] : 0;
    tmp[t] = v;
    __syncthreads();
    for (int off = 1; off < 256; off <<= 1) {
        int x = (t >= off) ? tmp[t - off] : 0;
        __syncthreads();
        tmp[t] += x;
        __syncthreads();
    }
    if (t < NB) part[t] = tmp[t] - v;   // exclusive block base
}

// Per-element exclusive scan -> base (pristine) + compact in_deg
__global__ void base_kernel(const int* __restrict__ in_deg_p, const int* __restrict__ part,
                            int* __restrict__ base, int* __restrict__ in_deg_c, int pad) {
    __shared__ int tmp[256];
    int t = threadIdx.x;
    int i = blockIdx.x * 256 + t;
    int v = (i < NN) ? in_deg_p[i * pad] : 0;
    tmp[t] = v;
    __syncthreads();
    for (int off = 1; off < 256; off <<= 1) {
        int x = (t >= off) ? tmp[t - off] : 0;
        __syncthreads();
        tmp[t] += x;
        __syncthreads();
    }
    if (i < NN) {
        base[i] = part[blockIdx.x] + tmp[t] - v;   // exclusive
        in_deg_c[i] = v;
    }
}

// Atomic-free counting-sort placement using precomputed ranks.
__global__ void place_kernel(const int* __restrict__ src, const int* __restrict__ dst,
                             const int* __restrict__ rank, const int* __restrict__ base,
                             int* __restrict__ sorted_src) {
    int e = blockIdx.x * blockDim.x + threadIdx.x;
    if (e < NE) {
        sorted_src[base[dst[e]] + rank[e]] = src[e];
    }
}

// h[n,:] = emb[feat[n],:] * out_deg_norm(n), stored bf16. One wave per node.
__global__ void h_kernel(const int* __restrict__ feat, const int* __restrict__ out_deg_p,
                         const float* __restrict__ emb, ushort2* __restrict__ h, int pad) {
    int wid = (blockIdx.x * blockDim.x + threadIdx.x) >> 6;
    int lane = threadIdx.x & 63;
    if (wid >= NN) return;
    int f = feat[wid];
    float nl = rsqrtf((float)max(out_deg_p[wid * pad], 1));
    float2 v = ((const float2*)(emb + (size_t)f * DD))[lane];
    h[(size_t)wid * 64 + lane] = make_ushort2(f2bf(v.x * nl), f2bf(v.y * nl));
}

// One wave per dst node. Indices batch-loaded (coalesced) and shfl-broadcast;
// row loop unrolled x4 for memory-level parallelism. fp32 accumulate.
__global__ void gatherA_kernel(const ushort2* __restrict__ h, const int* __restrict__ base,
                               const int* __restrict__ in_deg_c, const int* __restrict__ sorted,
                               const float* __restrict__ bias, float* __restrict__ out) {
    int wid = (blockIdx.x * blockDim.x + threadIdx.x) >> 6;
    int lane = threadIdx.x & 63;
    if (wid >= NN) return;
    int cnt = in_deg_c[wid];
    int beg = base[wid];
    float ax = 0.f, ay = 0.f;
    for (int b0 = 0; b0 < cnt; b0 += 64) {
        int m = min(cnt - b0, 64);
        int idx = (lane < m) ? sorted[beg + b0 + lane] : 0;
        int j = 0;
        for (; j + 3 < m; j += 4) {
            int s0 = __shfl(idx, j);
            int s1 = __shfl(idx, j + 1);
            int s2 = __shfl(idx, j + 2);
            int s3 = __shfl(idx, j + 3);
            ushort2 v0 = h[(size_t)s0 * 64 + lane];
            ushort2 v1 = h[(size_t)s1 * 64 + lane];
            ushort2 v2 = h[(size_t)s2 * 64 + lane];
            ushort2 v3 = h[(size_t)s3 * 64 + lane];
            ax += bf2f(v0.x) + bf2f(v1.x) + bf2f(v2.x) + bf2f(v3.x);
            ay += bf2f(v0.y) + bf2f(v1.y) + bf2f(v2.y) + bf2f(v3.y);
        }
        for (; j < m; j++) {
            int s0 = __shfl(idx, j);
            ushort2 v0 = h[(size_t)s0 * 64 + lane];
            ax += bf2f(v0.x);
            ay += bf2f(v0.y);
        }
    }
    float nr = rsqrtf((float)max(cnt, 1));
    float2 b = ((const float2*)bias)[lane];
    ((float2*)(out + (size_t)wid * DD))[lane] = make_float2(ax * nr + b.x, ay * nr + b.y);
}

// Fallback (small ws): gather straight from fp32 embedding with per-edge lookups.
__global__ void gatherB_kernel(const int* __restrict__ feat, const float* __restrict__ emb,
                               const int* __restrict__ out_deg_p, const int* __restrict__ base,
                               const int* __restrict__ in_deg_c, const int* __restrict__ sorted,
                               const float* __restrict__ bias, float* __restrict__ out, int pad) {
    int wid = (blockIdx.x * blockDim.x + threadIdx.x) >> 6;
    int lane = threadIdx.x & 63;
    if (wid >= NN) return;
    int cnt = in_deg_c[wid];
    int beg = base[wid];
    float2 acc = make_float2(0.f, 0.f);
    for (int j = 0; j < cnt; j++) {
        int s0 = sorted[beg + j];
        float nl0 = rsqrtf((float)max(out_deg_p[s0 * pad], 1));
        float2 v0 = ((const float2*)(emb + (size_t)feat[s0] * DD))[lane];
        acc.x += v0.x * nl0;
        acc.y += v0.y * nl0;
    }
    float nr = rsqrtf((float)max(cnt, 1));
    float2 b = ((const float2*)bias)[lane];
    ((float2*)(out + (size_t)wid * DD))[lane] = make_float2(acc.x * nr + b.x, acc.y * nr + b.y);
}

extern "C" void kernel_launch(void* const* d_in, const int* in_sizes, int n_in,
                              void* d_out, int out_size, void* d_ws, size_t ws_size,
                              hipStream_t stream) {
    const int* feat = (const int*)d_in[0];
    const int* src  = (const int*)d_in[1];
    const int* dst  = (const int*)d_in[2];
    const float* emb  = (const float*)d_in[3];
    const float* bias = (const float*)d_in[4];
    float* out = (float*)d_out;

    // Choose counter padding by available workspace.
    auto need = [](int pad, bool with_h) -> size_t {
        size_t ints = (size_t)2 * NN * pad + 2 * NN + 256 + 2 * NE;
        size_t bytes = ints * sizeof(int);
        if (with_h) bytes += (size_t)NN * 64 * sizeof(ushort2);
        return bytes;
    };
    int pad;
    bool with_h;
    if (ws_size >= need(8, true))      { pad = 8; with_h = true; }
    else if (ws_size >= need(1, true)) { pad = 1; with_h = true; }
    else                               { pad = 1; with_h = false; }

    int* out_deg_p = (int*)d_ws;                 // NN*pad
    int* in_deg_p  = out_deg_p + NN * pad;       // NN*pad
    int* base      = in_deg_p + NN * pad;        // NN
    int* in_deg_c  = base + NN;                  // NN
    int* part      = in_deg_c + NN;              // 256
    int* rank      = part + 256;                 // NE
    int* sorted    = rank + NE;                  // NE
    ushort2* h     = (ushort2*)(sorted + NE);    // NN*64 ushort2 = 12.8 MB

    // Zero the atomic counters (adjacent in memory -> one memset).
    hipMemsetAsync(out_deg_p, 0, (size_t)2 * NN * pad * sizeof(int), stream);

    degrank_kernel<<<(NE + 255) / 256, 256, 0, stream>>>(src, dst, out_deg_p, in_deg_p, rank, pad);
    partial_kernel<<<NB, 256, 0, stream>>>(in_deg_p, part, pad);
    scanpart_kernel<<<1, 256, 0, stream>>>(part);
    base_kernel<<<NB, 256, 0, stream>>>(in_deg_p, part, base, in_deg_c, pad);
    place_kernel<<<(NE + 255) / 256, 256, 0, stream>>>(src, dst, rank, base, sorted);

    int gblocks = (NN * 64 + 255) / 256;
    if (with_h) {
        h_kernel<<<gblocks, 256, 0, stream>>>(feat, out_deg_p, emb, h, pad);
        gatherA_kernel<<<gblocks, 256, 0, stream>>>(h, base, in_deg_c, sorted, bias, out);
    } else {
        gatherB_kernel<<<gblocks, 256, 0, stream>>>(feat, emb, out_deg_p, base, in_deg_c,
                                                    sorted, bias, out, pad);
    }
}

// Round 6
// 122.300 us; speedup vs baseline: 2.2534x; 1.2124x over previous
//
#include <hip/hip_runtime.h>

#define NN 50000
#define NE 800000
#define DD 128
#define BSH 7
#define BSZ 128                               // nodes per bucket
#define NBUCK ((NN + BSZ - 1) / BSZ)          // 391
#define NBLK 256                              // edge-partition blocks
#define EPB ((NE + NBLK - 1) / NBLK)          // 3125
#define CAP 4096                              // edges per LDS chunk in gather

__device__ __forceinline__ unsigned short f2bf(float x) {
    unsigned u = __float_as_uint(x);
    unsigned r = u + 0x7FFF + ((u >> 16) & 1);   // round-to-nearest-even
    return (unsigned short)(r >> 16);
}
__device__ __forceinline__ float bf2f(unsigned short x) {
    return __uint_as_float((unsigned)x << 16);
}

// K1: per-block LDS histograms of dst>>7 and src>>7 (no global atomics)
__global__ void hist_kernel(const int* __restrict__ src, const int* __restrict__ dst,
                            int* __restrict__ histD, int* __restrict__ histS) {
    __shared__ int hD[NBUCK], hS[NBUCK];
    int t = threadIdx.x, blk = blockIdx.x;
    for (int b = t; b < NBUCK; b += 256) { hD[b] = 0; hS[b] = 0; }
    __syncthreads();
    int beg = blk * EPB, end = min(beg + EPB, NE);
    for (int i = beg + t; i < end; i += 256) {
        atomicAdd(&hD[dst[i] >> BSH], 1);
        atomicAdd(&hS[src[i] >> BSH], 1);
    }
    __syncthreads();
    for (int b = t; b < NBUCK; b += 256) {
        histD[b * NBLK + blk] = hD[b];
        histS[b * NBLK + blk] = hS[b];
    }
}

// K2a: per-bin totals (both tables; blockIdx selects table+bin)
__global__ void binsum_kernel(const int* __restrict__ histD, const int* __restrict__ histS,
                              int* __restrict__ SD, int* __restrict__ SS) {
    __shared__ int tmp[256];
    int t = threadIdx.x, b = blockIdx.x;
    const int* hist = (b < NBUCK) ? histD : histS;
    int* S = (b < NBUCK) ? SD : SS;
    int bin = (b < NBUCK) ? b : b - NBUCK;
    tmp[t] = hist[bin * NBLK + t];
    __syncthreads();
    for (int off = 128; off > 0; off >>= 1) {
        if (t < off) tmp[t] += tmp[t + off];
        __syncthreads();
    }
    if (t == 0) S[bin] = tmp[0];
}

// K2b: offsets[bin][blk] = binBase(bin) + prefix_within_bin(blk); in-place on hist.
__global__ void offsets_kernel(int* __restrict__ histD, int* __restrict__ histS,
                               const int* __restrict__ SD, const int* __restrict__ SS,
                               int* __restrict__ baseD, int* __restrict__ baseS) {
    __shared__ int s[512];
    __shared__ int col[NBLK];
    int t = threadIdx.x, b = blockIdx.x;
    int* hist = (b < NBUCK) ? histD : histS;
    const int* S = (b < NBUCK) ? SD : SS;
    int* base = (b < NBUCK) ? baseD : baseS;
    int bin = (b < NBUCK) ? b : b - NBUCK;
    s[t] = (t < NBUCK) ? S[t] : 0;
    __syncthreads();
    for (int off = 1; off < 512; off <<= 1) {
        int x = (t >= off) ? s[t - off] : 0;
        __syncthreads();
        s[t] += x;
        __syncthreads();
    }
    int binBase = s[bin] - S[bin];   // exclusive across bins
    if (t < NBLK) col[t] = hist[bin * NBLK + t];
    __syncthreads();
    int cv = (t < NBLK) ? col[t] : 0;
    for (int off = 1; off < NBLK; off <<= 1) {
        int x = (t < NBLK && t >= off) ? col[t - off] : 0;
        __syncthreads();
        if (t < NBLK) col[t] += x;
        __syncthreads();
    }
    if (t < NBLK) hist[bin * NBLK + t] = binBase + col[t] - cv;   // exclusive within bin
    if (t == 0) base[bin] = binBase;
}

// K3: scatter edges into dst-buckets (packed src|lo<<16) and src_lo bytes into src-buckets.
__global__ void scatter_kernel(const int* __restrict__ src, const int* __restrict__ dst,
                               const int* __restrict__ offsD, const int* __restrict__ offsS,
                               unsigned int* __restrict__ sortedD,
                               unsigned char* __restrict__ sortedS) {
    __shared__ int curD[NBUCK], curS[NBUCK];
    int t = threadIdx.x, blk = blockIdx.x;
    for (int b = t; b < NBUCK; b += 256) {
        curD[b] = offsD[b * NBLK + blk];
        curS[b] = offsS[b * NBLK + blk];
    }
    __syncthreads();
    int beg = blk * EPB, end = min(beg + EPB, NE);
    for (int i = beg + t; i < end; i += 256) {
        int sv = src[i], dv = dst[i];
        int pD = atomicAdd(&curD[dv >> BSH], 1);
        sortedD[pD] = (unsigned)sv | ((unsigned)(dv & (BSZ - 1)) << 16);
        int pS = atomicAdd(&curS[sv >> BSH], 1);
        sortedS[pS] = (unsigned char)(sv & (BSZ - 1));
    }
}

// K4s: per src-bucket: LDS out-degree histogram -> build bf16 h rows (fused norm_l).
__global__ void hbuild_kernel(const unsigned char* __restrict__ sortedS,
                              const int* __restrict__ baseS, const int* __restrict__ feat,
                              const float* __restrict__ emb, ushort2* __restrict__ h) {
    __shared__ int hc[BSZ];
    int t = threadIdx.x, bin = blockIdx.x;
    if (t < BSZ) hc[t] = 0;
    __syncthreads();
    int beg = baseS[bin];
    int end = (bin == NBUCK - 1) ? NE : baseS[bin + 1];
    for (int i = beg + t; i < end; i += 256) atomicAdd(&hc[sortedS[i]], 1);
    __syncthreads();
    int w = t >> 6, lane = t & 63;
    for (int lo = w; lo < BSZ; lo += 4) {
        int n = (bin << BSH) + lo;
        if (n >= NN) break;
        float nl = rsqrtf((float)max(hc[lo], 1));
        int f = feat[n];
        float2 v = ((const float2*)(emb + (size_t)f * DD))[lane];
        h[(size_t)n * 64 + lane] = make_ushort2(f2bf(v.x * nl), f2bf(v.y * nl));
    }
}

// K4: per dst-bucket: LDS counting-sort by dst_lo, then 16 waves gather h rows,
// fused norm_r + bias, single coalesced output write.
__global__ void __launch_bounds__(1024) gather_kernel(
        const unsigned int* __restrict__ sortedD, const int* __restrict__ baseD,
        const ushort2* __restrict__ h, const float* __restrict__ bias,
        float* __restrict__ out) {
    __shared__ unsigned short eds[CAP];
    __shared__ int lh[BSZ], lbase[BSZ], lcur[BSZ];
    int t = threadIdx.x, bin = blockIdx.x;
    int w = t >> 6, lane = t & 63;
    int beg = baseD[bin];
    int end = (bin == NBUCK - 1) ? NE : baseD[bin + 1];
    float2 acc[8];
    int tcnt[8];
    for (int k = 0; k < 8; k++) { acc[k] = make_float2(0.f, 0.f); tcnt[k] = 0; }
    for (int cb = beg; cb < end; cb += CAP) {
        int m = min(end - cb, CAP);
        if (t < BSZ) lh[t] = 0;
        __syncthreads();
        unsigned int er[4];
        int nt = 0;
        for (int i = t; i < m; i += 1024) {
            unsigned int e = sortedD[cb + i];
            er[nt++] = e;
            atomicAdd(&lh[e >> 16], 1);
        }
        __syncthreads();
        int cv = (t < BSZ) ? lh[t] : 0;
        if (t < BSZ) lbase[t] = cv;
        __syncthreads();
        for (int off = 1; off < BSZ; off <<= 1) {
            int x = (t < BSZ && t >= off) ? lbase[t - off] : 0;
            __syncthreads();
            if (t < BSZ) lbase[t] += x;
            __syncthreads();
        }
        if (t < BSZ) { lbase[t] -= cv; lcur[t] = lbase[t]; }
        __syncthreads();
        for (int j = 0; j < nt; j++) {
            int pos = atomicAdd(&lcur[er[j] >> 16], 1);
            eds[pos] = (unsigned short)(er[j] & 0xFFFF);
        }
        __syncthreads();
        for (int k = 0; k < 8; k++) {
            int lo = w + (k << 4);
            int c = lh[lo], b0 = lbase[lo];
            tcnt[k] += c;
            for (int j = 0; j < c; j++) {
                int sidx = eds[b0 + j];                       // LDS broadcast
                ushort2 hv = h[(size_t)sidx * 64 + lane];     // coalesced 256B row
                acc[k].x += bf2f(hv.x);
                acc[k].y += bf2f(hv.y);
            }
        }
        __syncthreads();
    }
    float2 bi = ((const float2*)bias)[lane];
    for (int k = 0; k < 8; k++) {
        int lo = w + (k << 4);
        int n = (bin << BSH) + lo;
        if (n < NN) {
            float nr = rsqrtf((float)max(tcnt[k], 1));
            ((float2*)(out + (size_t)n * DD))[lane] =
                make_float2(acc[k].x * nr + bi.x, acc[k].y * nr + bi.y);
        }
    }
}

extern "C" void kernel_launch(void* const* d_in, const int* in_sizes, int n_in,
                              void* d_out, int out_size, void* d_ws, size_t ws_size,
                              hipStream_t stream) {
    const int* feat = (const int*)d_in[0];
    const int* src  = (const int*)d_in[1];
    const int* dst  = (const int*)d_in[2];
    const float* emb  = (const float*)d_in[3];
    const float* bias = (const float*)d_in[4];
    float* out = (float*)d_out;

    // Workspace layout (all int-aligned; total ~17.6 MB)
    int* histD = (int*)d_ws;                         // NBUCK*NBLK
    int* histS = histD + NBUCK * NBLK;               // NBUCK*NBLK
    int* SD    = histS + NBUCK * NBLK;               // NBUCK (padded 400)
    int* SS    = SD + 400;                           // NBUCK
    int* baseD = SS + 400;                           // NBUCK
    int* baseS = baseD + 400;                        // NBUCK
    unsigned int*  sortedD = (unsigned int*)(baseS + 400);   // NE
    unsigned char* sortedS = (unsigned char*)(sortedD + NE); // NE bytes
    ushort2* h = (ushort2*)(sortedS + NE);           // NN*64 ushort2 (12.8 MB)

    hist_kernel<<<NBLK, 256, 0, stream>>>(src, dst, histD, histS);
    binsum_kernel<<<2 * NBUCK, 256, 0, stream>>>(histD, histS, SD, SS);
    offsets_kernel<<<2 * NBUCK, 512, 0, stream>>>(histD, histS, SD, SS, baseD, baseS);
    scatter_kernel<<<NBLK, 256, 0, stream>>>(src, dst, histD, histS, sortedD, sortedS);
    hbuild_kernel<<<NBUCK, 256, 0, stream>>>(sortedS, baseS, feat, emb, h);
    gather_kernel<<<NBUCK, 1024, 0, stream>>>(sortedD, baseD, h, bias, out);
}